// Round 5
// baseline (36.120 us; speedup 1.0000x reference)
//
#include <hip/hip_runtime.h>

// Problem constants (fixed by the reference):
//   B=64, L=2048, D=1024, seq f32, begin/end int32 (harness downcasts int64),
//   out f32 [B, D]
#define B_ 64
#define L_ 2048
#define D_ 1024
#define SPLIT 64   // span slices per batch -> stage1 grid 64x64 = 4096 blocks
                   // (2x resident capacity -> dynamic load balancing; quantum <=16 rows)

// Stage 1: block (b,s) accumulates rows [bg + s*per, ...) of batch b and
// stores a pre-scaled partial (zeros if slice empty) to ws[b][s][0..D).
// Plain float4 stores — NO atomics.
__global__ __launch_bounds__(256) void seg_mean_stage1(
    const float* __restrict__ seq,
    const int* __restrict__ begin,
    const int* __restrict__ end,
    float* __restrict__ ws)
{
    const int b  = blockIdx.x;
    const int s  = blockIdx.y;
    const int bg = begin[b];
    const int en = end[b];
    const int len = en - bg;             // >= 1

    const int per = (len + SPLIT - 1) / SPLIT;
    const int l0  = bg + s * per;
    const int l1  = min(l0 + per, en);

    const int col = threadIdx.x;         // one float4 of the D=1024 row
    const float4* __restrict__ base =
        reinterpret_cast<const float4*>(seq + (size_t)b * L_ * D_);

    float4 a0 = make_float4(0.f, 0.f, 0.f, 0.f);
    float4 a1 = a0, a2 = a0, a3 = a0;

    int l = l0;
    for (; l + 4 <= l1; l += 4) {        // 4 independent 16B loads in flight
        float4 v0 = base[(size_t)(l + 0) * (D_ / 4) + col];
        float4 v1 = base[(size_t)(l + 1) * (D_ / 4) + col];
        float4 v2 = base[(size_t)(l + 2) * (D_ / 4) + col];
        float4 v3 = base[(size_t)(l + 3) * (D_ / 4) + col];
        a0.x += v0.x; a0.y += v0.y; a0.z += v0.z; a0.w += v0.w;
        a1.x += v1.x; a1.y += v1.y; a1.z += v1.z; a1.w += v1.w;
        a2.x += v2.x; a2.y += v2.y; a2.z += v2.z; a2.w += v2.w;
        a3.x += v3.x; a3.y += v3.y; a3.z += v3.z; a3.w += v3.w;
    }
    for (; l < l1; ++l) {
        float4 v = base[(size_t)l * (D_ / 4) + col];
        a0.x += v.x; a0.y += v.y; a0.z += v.z; a0.w += v.w;
    }

    const float inv = 1.0f / (float)len; // pre-scale so stage2 is a plain sum
    float4 t;
    t.x = (a0.x + a1.x + a2.x + a3.x) * inv;
    t.y = (a0.y + a1.y + a2.y + a3.y) * inv;
    t.z = (a0.z + a1.z + a2.z + a3.z) * inv;
    t.w = (a0.w + a1.w + a2.w + a3.w) * inv;

    float4* __restrict__ w4 = reinterpret_cast<float4*>(ws);
    w4[((size_t)(b * SPLIT + s)) * (D_ / 4) + col] = t;   // unconditional
}

// Stage 2: block b, thread col sums ws[b][0..SPLIT)[col4] and overwrites out.
__global__ __launch_bounds__(256) void seg_mean_stage2(
    const float* __restrict__ ws,
    float* __restrict__ out)
{
    const int b   = blockIdx.x;
    const int col = threadIdx.x;
    const float4* __restrict__ w4 =
        reinterpret_cast<const float4*>(ws) + (size_t)b * SPLIT * (D_ / 4);

    float4 acc = make_float4(0.f, 0.f, 0.f, 0.f);
    #pragma unroll
    for (int s = 0; s < SPLIT; ++s) {
        float4 v = w4[(size_t)s * (D_ / 4) + col];
        acc.x += v.x; acc.y += v.y; acc.z += v.z; acc.w += v.w;
    }
    reinterpret_cast<float4*>(out)[(size_t)b * (D_ / 4) + col] = acc;
}

extern "C" void kernel_launch(void* const* d_in, const int* in_sizes, int n_in,
                              void* d_out, int out_size, void* d_ws, size_t ws_size,
                              hipStream_t stream) {
    const float* seq   = (const float*)d_in[0];
    const int*   begin = (const int*)d_in[1];   // int32: harness downcasts jnp.int64
    const int*   end   = (const int*)d_in[2];
    float*       out   = (float*)d_out;
    float*       ws    = (float*)d_ws;          // needs 64*64*1024*4 = 16 MB

    dim3 g1(B_, SPLIT);
    seg_mean_stage1<<<g1, 256, 0, stream>>>(seq, begin, end, ws);
    seg_mean_stage2<<<B_, 256, 0, stream>>>(ws, out);
}

// Round 6
// 32.759 us; speedup vs baseline: 1.1026x; 1.1026x over previous
//
#include <hip/hip_runtime.h>

// Problem constants (fixed by the reference):
//   B=64, L=2048, D=1024, seq f32, begin/end int32 (harness downcasts int64),
//   out f32 [B, D]
#define B_ 64
#define L_ 2048
#define D_ 1024
#define SPLIT 64   // span slices per batch -> stage1 grid 64x64 = 4096 blocks
// Grid is (SPLIT, B_): linear id = s + 64*b. With round-robin CU fill (stride
// 256), CU c gets b = c/64 + 4k -> 16 DISTINCT batches per CU. The previous
// (B_, SPLIT) mapping had b = c mod 64: one batch per CU -> per-CU work
// proportional to len_b (2x makespan). This swap is the load-balance fix.

// Stage 1: block (s,b) accumulates rows [bg + s*per, ...) of batch b and
// stores a pre-scaled partial (zeros if slice empty) to ws[b][s][0..D).
__global__ __launch_bounds__(256) void seg_mean_stage1(
    const float* __restrict__ seq,
    const int* __restrict__ begin,
    const int* __restrict__ end,
    float* __restrict__ ws)
{
    const int s  = blockIdx.x;
    const int b  = blockIdx.y;
    const int bg = begin[b];
    const int en = end[b];
    const int len = en - bg;             // >= 1

    const int per = (len + SPLIT - 1) / SPLIT;
    const int l0  = bg + s * per;
    const int l1  = min(l0 + per, en);

    const int col = threadIdx.x;         // one float4 of the D=1024 row
    const float4* __restrict__ base =
        reinterpret_cast<const float4*>(seq + (size_t)b * L_ * D_);

    float4 a0 = make_float4(0.f, 0.f, 0.f, 0.f);
    float4 a1 = a0, a2 = a0, a3 = a0;

    int l = l0;
    for (; l + 4 <= l1; l += 4) {        // 4 independent 16B loads in flight
        float4 v0 = base[(size_t)(l + 0) * (D_ / 4) + col];
        float4 v1 = base[(size_t)(l + 1) * (D_ / 4) + col];
        float4 v2 = base[(size_t)(l + 2) * (D_ / 4) + col];
        float4 v3 = base[(size_t)(l + 3) * (D_ / 4) + col];
        a0.x += v0.x; a0.y += v0.y; a0.z += v0.z; a0.w += v0.w;
        a1.x += v1.x; a1.y += v1.y; a1.z += v1.z; a1.w += v1.w;
        a2.x += v2.x; a2.y += v2.y; a2.z += v2.z; a2.w += v2.w;
        a3.x += v3.x; a3.y += v3.y; a3.z += v3.z; a3.w += v3.w;
    }
    for (; l < l1; ++l) {
        float4 v = base[(size_t)l * (D_ / 4) + col];
        a0.x += v.x; a0.y += v.y; a0.z += v.z; a0.w += v.w;
    }

    const float inv = 1.0f / (float)len; // pre-scale so stage2 is a plain sum
    float4 t;
    t.x = (a0.x + a1.x + a2.x + a3.x) * inv;
    t.y = (a0.y + a1.y + a2.y + a3.y) * inv;
    t.z = (a0.z + a1.z + a2.z + a3.z) * inv;
    t.w = (a0.w + a1.w + a2.w + a3.w) * inv;

    float4* __restrict__ w4 = reinterpret_cast<float4*>(ws);
    w4[((size_t)(b * SPLIT + s)) * (D_ / 4) + col] = t;   // unconditional
}

// Stage 2: block b, thread col sums ws[b][0..SPLIT)[col4] and overwrites out.
__global__ __launch_bounds__(256) void seg_mean_stage2(
    const float* __restrict__ ws,
    float* __restrict__ out)
{
    const int b   = blockIdx.x;
    const int col = threadIdx.x;
    const float4* __restrict__ w4 =
        reinterpret_cast<const float4*>(ws) + (size_t)b * SPLIT * (D_ / 4);

    float4 acc = make_float4(0.f, 0.f, 0.f, 0.f);
    #pragma unroll
    for (int s = 0; s < SPLIT; ++s) {
        float4 v = w4[(size_t)s * (D_ / 4) + col];
        acc.x += v.x; acc.y += v.y; acc.z += v.z; acc.w += v.w;
    }
    reinterpret_cast<float4*>(out)[(size_t)b * (D_ / 4) + col] = acc;
}

extern "C" void kernel_launch(void* const* d_in, const int* in_sizes, int n_in,
                              void* d_out, int out_size, void* d_ws, size_t ws_size,
                              hipStream_t stream) {
    const float* seq   = (const float*)d_in[0];
    const int*   begin = (const int*)d_in[1];   // int32: harness downcasts jnp.int64
    const int*   end   = (const int*)d_in[2];
    float*       out   = (float*)d_out;
    float*       ws    = (float*)d_ws;          // needs 64*64*1024*4 = 16 MB

    dim3 g1(SPLIT, B_);                         // s fastest -> de-alias batch->CU
    seg_mean_stage1<<<g1, 256, 0, stream>>>(seq, begin, end, ws);
    seg_mean_stage2<<<B_, 256, 0, stream>>>(ws, out);
}